// Round 1
// baseline (382.465 us; speedup 1.0000x reference)
//
#include <hip/hip_runtime.h>

#define NUM_REGIONS 32
#define NBINS 33          // regions 0..32 (0 is ignored in the loss)
#define BATCH 4
#define DHW (160*192*192) // 5,898,240 elements per volume, divisible by 4
#define EPS 1e-8f

// ---------------------------------------------------------------------------
// Kernel 1: sigmoid + per-(batch, region) segment sums into global ws bins.
// ws layout: ws[0 .. BATCH*NBINS)            = xs   (sum of sigmoid)
//            ws[BATCH*NBINS .. 2*BATCH*NBINS) = cnt  (element counts, as float)
// ---------------------------------------------------------------------------
__global__ __launch_bounds__(256) void region_sums_kernel(
    const float* __restrict__ x,
    const int*   __restrict__ seg,
    float*       __restrict__ ws)
{
    __shared__ float s_xs [BATCH * NBINS];
    __shared__ float s_cnt[BATCH * NBINS];
    for (int i = threadIdx.x; i < BATCH * NBINS; i += 256) {
        s_xs[i]  = 0.0f;
        s_cnt[i] = 0.0f;
    }
    __syncthreads();

    const int nvec = (BATCH * DHW) / 4;      // 5,898,240 float4 / int4 vectors
    const float4* __restrict__ xv4 = (const float4*)x;
    const int4*   __restrict__ sv4 = (const int4*)seg;

    const int stride = gridDim.x * 256;
    for (int v = blockIdx.x * 256 + threadIdx.x; v < nvec; v += stride) {
        float4 xv = xv4[v];
        int4   sv = sv4[v];

        // batch index of this vector (DHW % 4 == 0, so a vector never straddles)
        int b    = (int)(((unsigned)v * 4u) / (unsigned)DHW);
        int base = b * NBINS;

        // sigmoid(x) = 1 / (1 + exp(-x)); fast exp + fast divide (memory-bound,
        // error ~1e-6 relative, threshold is 6.7e-3 on the scalar output)
        float p0 = __fdividef(1.0f, 1.0f + __expf(-xv.x));
        float p1 = __fdividef(1.0f, 1.0f + __expf(-xv.y));
        float p2 = __fdividef(1.0f, 1.0f + __expf(-xv.z));
        float p3 = __fdividef(1.0f, 1.0f + __expf(-xv.w));

        atomicAdd(&s_xs [base + sv.x], p0);
        atomicAdd(&s_cnt[base + sv.x], 1.0f);
        atomicAdd(&s_xs [base + sv.y], p1);
        atomicAdd(&s_cnt[base + sv.y], 1.0f);
        atomicAdd(&s_xs [base + sv.z], p2);
        atomicAdd(&s_cnt[base + sv.z], 1.0f);
        atomicAdd(&s_xs [base + sv.w], p3);
        atomicAdd(&s_cnt[base + sv.w], 1.0f);
    }
    __syncthreads();

    // One global atomic per touched bin per block (device-scope by default).
    for (int i = threadIdx.x; i < BATCH * NBINS; i += 256) {
        float c = s_cnt[i];
        if (c != 0.0f) {
            atomicAdd(&ws[i], s_xs[i]);
            atomicAdd(&ws[BATCH * NBINS + i], c);
        }
    }
}

// ---------------------------------------------------------------------------
// Kernel 2: dice + mean epilogue. One wave; lane r handles region r (1..32).
// ---------------------------------------------------------------------------
__global__ void region_dice_final_kernel(
    const float* __restrict__ ws,
    float*       __restrict__ out)
{
    const int lane = threadIdx.x;   // 0..63
    float loss_sum = 0.0f;

    for (int b = 0; b < BATCH; ++b) {
        bool  valid = false;
        float dice  = 0.0f;
        if (lane >= 1 && lane <= NUM_REGIONS) {
            float xs  = ws[b * NBINS + lane];
            float cnt = ws[BATCH * NBINS + b * NBINS + lane];
            valid = (cnt > 0.0f);
            if (valid) dice = 2.0f * xs / (xs + cnt + EPS);
        }
        unsigned long long m = __ballot(valid);
        int n_valid = __popcll(m);

        float s = dice;
        #pragma unroll
        for (int off = 32; off >= 1; off >>= 1) s += __shfl_down(s, off);
        // lane 0 now holds the full sum over valid regions

        float mean_dice = s / (float)((n_valid > 1) ? n_valid : 1);
        float loss_b    = (n_valid > 0) ? (1.0f - mean_dice) : 1.0f;
        loss_sum += loss_b;
    }

    if (lane == 0) out[0] = loss_sum * (1.0f / BATCH);
}

extern "C" void kernel_launch(void* const* d_in, const int* in_sizes, int n_in,
                              void* d_out, int out_size, void* d_ws, size_t ws_size,
                              hipStream_t stream)
{
    const float* x   = (const float*)d_in[0];
    const int*   seg = (const int*)d_in[1];
    float*       ws  = (float*)d_ws;

    // d_ws is poisoned with 0xAA before every timed launch — zero the bins.
    hipMemsetAsync(d_ws, 0, 2 * BATCH * NBINS * sizeof(float), stream);

    region_sums_kernel<<<2048, 256, 0, stream>>>(x, seg, ws);
    region_dice_final_kernel<<<1, 64, 0, stream>>>(ws, (float*)d_out);
}

// Round 2
// 223.582 us; speedup vs baseline: 1.7106x; 1.7106x over previous
//
#include <hip/hip_runtime.h>

#define NUM_REGIONS 32
#define NBINS 33                      // regions 0..32 (0 dropped in the loss)
#define BATCH 4
#define DHW (160*192*192)             // 5,898,240 per volume, divisible by 4
#define NVEC_PER_BATCH (DHW/4)        // 1,474,560 float4 vectors per batch
#define BLOCKS_PER_BATCH 512
#define NBLOCKS (BATCH*BLOCKS_PER_BATCH)            // 2048
#define VEC_PER_BLOCK (NVEC_PER_BATCH/BLOCKS_PER_BATCH) // 2880 exactly
#define LDS_STRIDE 257                // 257 % 32 == 1 -> bank = (bin+tid)%32
#define EPS 1e-8f

// ---------------------------------------------------------------------------
// Kernel 1: per-thread privatized LDS histogram, NO atomics in the hot loop.
// Each thread accumulates V[bin] = sum(sigmoid(x)) + 256 * count into its own
// LDS column. count recovered as floor(V/256) at reduce time (xs_part < 48).
// ws layout: ws[0..132) = xs sums, ws[132..264) = counts (as float).
// ---------------------------------------------------------------------------
__global__ __launch_bounds__(256) void region_sums_kernel(
    const float* __restrict__ x,
    const int*   __restrict__ seg,
    float*       __restrict__ ws)
{
    __shared__ float hist[NBINS * LDS_STRIDE];   // 33*257*4 = 33,924 B
    const int tid = threadIdx.x;

    for (int i = tid; i < NBINS * LDS_STRIDE; i += 256) hist[i] = 0.0f;
    __syncthreads();

    const int  batch = blockIdx.x >> 9;          // 512 blocks per batch
    const int  local = blockIdx.x & 511;
    const long vbase = (long)batch * NVEC_PER_BATCH + (long)local * VEC_PER_BLOCK;

    const float4* __restrict__ xv4 = (const float4*)x;
    const int4*   __restrict__ sv4 = (const int4*)seg;

    // manual 1-deep prefetch so next global loads overlap the DS RMW chain
    int    v  = tid;                              // tid < 2880 always
    float4 xv = xv4[vbase + v];
    int4   sv = sv4[vbase + v];

    while (true) {
        int vn = v + 256;
        float4 xvn; int4 svn;
        bool more = (vn < VEC_PER_BLOCK);
        if (more) { xvn = xv4[vbase + vn]; svn = sv4[vbase + vn]; }

        // packed accumulate: sigmoid(x) + 256 (count in the high part)
        float p0 = __fdividef(1.0f, 1.0f + __expf(-xv.x)) + 256.0f;
        float p1 = __fdividef(1.0f, 1.0f + __expf(-xv.y)) + 256.0f;
        float p2 = __fdividef(1.0f, 1.0f + __expf(-xv.z)) + 256.0f;
        float p3 = __fdividef(1.0f, 1.0f + __expf(-xv.w)) + 256.0f;

        hist[sv.x * LDS_STRIDE + tid] += p0;
        hist[sv.y * LDS_STRIDE + tid] += p1;
        hist[sv.z * LDS_STRIDE + tid] += p2;
        hist[sv.w * LDS_STRIDE + tid] += p3;

        if (!more) break;
        v = vn; xv = xvn; sv = svn;
    }
    __syncthreads();

    // block reduce: lane r (1..32) sums bin r across all 256 columns,
    // unpacking count = floor(V/256), xs = V - 256*count.
    if (tid >= 1 && tid <= NUM_REGIONS) {
        float xs = 0.0f, cnt = 0.0f;
        #pragma unroll 8
        for (int t = 0; t < 256; ++t) {
            float V = hist[tid * LDS_STRIDE + t];
            float c = floorf(V * (1.0f / 256.0f));
            cnt += c;
            xs  += V - 256.0f * c;
        }
        atomicAdd(&ws[batch * NBINS + tid], xs);
        atomicAdd(&ws[BATCH * NBINS + batch * NBINS + tid], cnt);
    }
}

// ---------------------------------------------------------------------------
// Kernel 2: dice + mean epilogue. One wave; lane r handles region r (1..32).
// ---------------------------------------------------------------------------
__global__ void region_dice_final_kernel(
    const float* __restrict__ ws,
    float*       __restrict__ out)
{
    const int lane = threadIdx.x;   // 0..63
    float loss_sum = 0.0f;

    for (int b = 0; b < BATCH; ++b) {
        bool  valid = false;
        float dice  = 0.0f;
        if (lane >= 1 && lane <= NUM_REGIONS) {
            float xs  = ws[b * NBINS + lane];
            float cnt = ws[BATCH * NBINS + b * NBINS + lane];
            valid = (cnt > 0.0f);
            if (valid) dice = 2.0f * xs / (xs + cnt + EPS);
        }
        unsigned long long m = __ballot(valid);
        int n_valid = __popcll(m);

        float s = dice;
        #pragma unroll
        for (int off = 32; off >= 1; off >>= 1) s += __shfl_down(s, off);

        float mean_dice = s / (float)((n_valid > 1) ? n_valid : 1);
        float loss_b    = (n_valid > 0) ? (1.0f - mean_dice) : 1.0f;
        loss_sum += loss_b;
    }

    if (lane == 0) out[0] = loss_sum * (1.0f / BATCH);
}

extern "C" void kernel_launch(void* const* d_in, const int* in_sizes, int n_in,
                              void* d_out, int out_size, void* d_ws, size_t ws_size,
                              hipStream_t stream)
{
    const float* x   = (const float*)d_in[0];
    const int*   seg = (const int*)d_in[1];
    float*       ws  = (float*)d_ws;

    // d_ws is poisoned with 0xAA before every timed launch — zero the bins.
    hipMemsetAsync(d_ws, 0, 2 * BATCH * NBINS * sizeof(float), stream);

    region_sums_kernel<<<NBLOCKS, 256, 0, stream>>>(x, seg, ws);
    region_dice_final_kernel<<<1, 64, 0, stream>>>(ws, (float*)d_out);
}